// Round 5
// baseline (1264.052 us; speedup 1.0000x reference)
//
#include <hip/hip_runtime.h>
#include <hip/hip_bf16.h>
#include <math.h>

#define NBLK 512
#define MAXNC 512  // supports N up to 131072 (256 nodes per coarse bucket)

// ---------------- pass A: coarse histogram per block chunk ----------------
__global__ void k_hist(const int* __restrict__ dst, int* __restrict__ hist,
                       int nE, int nc, int chunk) {
    __shared__ int ch[MAXNC];
    int b = blockIdx.x, t = threadIdx.x;
    for (int i = t; i < nc; i += 256) ch[i] = 0;
    __syncthreads();
    int c0 = b * chunk, c1 = min(nE, c0 + chunk);
    for (int e = c0 + t; e < c1; e += 256) atomicAdd(&ch[dst[e] >> 8], 1);
    __syncthreads();
    for (int i = t; i < nc; i += 256) hist[b * nc + i] = ch[i];
}

// ---------------- pass B: per-(block,cb) offsets + cbase scan ----------------
__global__ void k_scan(const int* __restrict__ hist, int* __restrict__ off,
                       int* __restrict__ cbase, int* __restrict__ rowstart,
                       int nE, int nc, int n) {
    __shared__ int sc[512];
    int t = threadIdx.x;  // 512
    int run = 0;
    if (t < nc) {
#pragma unroll 8
        for (int b = 0; b < NBLK; ++b) {
            off[b * nc + t] = run;
            run += hist[b * nc + t];
        }
    }
    sc[t] = (t < nc) ? run : 0;
    __syncthreads();
    for (int d = 1; d < 512; d <<= 1) {
        int v = (t >= d) ? sc[t - d] : 0;
        __syncthreads();
        sc[t] += v;
        __syncthreads();
    }
    if (t < nc) cbase[t] = sc[t] - run;
    if (t == 0) { cbase[nc] = nE; rowstart[n] = nE; }
}

// ---------------- pass C: deterministic scatter into coarse buckets ----------------
__global__ void k_fill(const int* __restrict__ src, const int* __restrict__ dst,
                       const int* __restrict__ off, const int* __restrict__ cbase,
                       int* __restrict__ bucketed, int nE, int nc, int chunk) {
    __shared__ int cur[MAXNC];
    int b = blockIdx.x, t = threadIdx.x;
    for (int i = t; i < nc; i += 256) cur[i] = cbase[i] + off[b * nc + i];
    __syncthreads();
    int c0 = b * chunk, c1 = min(nE, c0 + chunk);
    for (int e = c0 + t; e < c1; e += 256) {
        int d = dst[e];
        int entry = src[e] | ((d & 255) << 17);
        int pos = atomicAdd(&cur[d >> 8], 1);
        bucketed[pos] = entry;
    }
}

// ---------------- pass D: within-bucket sort to per-node CSR + rowstart/dinv ----------------
__global__ void k_fine(const int* __restrict__ bucketed, const int* __restrict__ cbase,
                       int* __restrict__ csr, int* __restrict__ rowstart,
                       float* __restrict__ dinv, int n) {
    __shared__ int cnt[256];
    __shared__ int lrs[256];
    __shared__ int cur[256];
    int cb = blockIdx.x, t = threadIdx.x;
    int e0 = cbase[cb], e1 = cbase[cb + 1];
    cnt[t] = 0;
    __syncthreads();
    for (int e = e0 + t; e < e1; e += 256) atomicAdd(&cnt[(bucketed[e] >> 17) & 255], 1);
    __syncthreads();
    int my = cnt[t];
    lrs[t] = my;
    __syncthreads();
    for (int d = 1; d < 256; d <<= 1) {
        int v = (t >= d) ? lrs[t - d] : 0;
        __syncthreads();
        lrs[t] += v;
        __syncthreads();
    }
    int excl = lrs[t] - my;
    int node = cb * 256 + t;
    if (node < n) {
        rowstart[node] = e0 + excl;
        dinv[node] = rsqrtf((float)(my + 1));
    }
    cur[t] = e0 + excl;
    __syncthreads();
    for (int e = e0 + t; e < e1; e += 256) {
        int entry = bucketed[e];
        int pos = atomicAdd(&cur[(entry >> 17) & 255], 1);
        csr[pos] = entry & 0x1FFFF;
    }
}

// ---------------- conv: wave per node, 16 edge-slots x 4 lanes x float4 ----------------
template <int MODE>
__global__ void k_conv(const float* __restrict__ hin, const int* __restrict__ csr,
                       const int* __restrict__ rowstart, const float* __restrict__ dinv,
                       const float* __restrict__ Wa, const float* __restrict__ ba,
                       const float* __restrict__ Wb,
                       float* __restrict__ hout, int n) {
    int wid = (blockIdx.x * blockDim.x + threadIdx.x) >> 6;
    if (wid >= n) return;
    int lane = threadIdx.x & 63;
    int q = lane >> 2;
    int c = lane & 3;
    int r0 = rowstart[wid], r1 = rowstart[wid + 1];
    int cnt = r1 - r0;
    const int* p = csr + r0 + q;
    int my = (cnt > q) ? ((cnt - q + 15) >> 4) : 0;

    float av[4] = {0.f, 0.f, 0.f, 0.f};
    int s0 = (my > 0) ? p[0] : 0;
    int s1 = (my > 1) ? p[16] : 0;
    for (int t = 0; t < my; ++t) {
        int scur = s0;
        s0 = s1;
        s1 = (t + 2 < my) ? p[(t + 2) * 16] : 0;
        float w = (MODE == 0) ? dinv[scur] : 1.0f;
        float4 v = *(const float4*)(hin + scur * 16 + c * 4);
        av[0] += w * v.x; av[1] += w * v.y; av[2] += w * v.z; av[3] += w * v.w;
    }
#pragma unroll
    for (int m = 4; m <= 32; m <<= 1) {
#pragma unroll
        for (int j = 0; j < 4; ++j) av[j] += __shfl_xor(av[j], m);
    }

    float4 hv4 = *(const float4*)(hin + wid * 16 + c * 4);
    float hvv[4] = {hv4.x, hv4.y, hv4.z, hv4.w};

    if (MODE == 0) {
        float di = dinv[wid];
        float di2 = di * di;
#pragma unroll
        for (int j = 0; j < 4; ++j) av[j] = di * av[j] + di2 * hvv[j];
    } else {
        float inv = 1.0f / fmaxf((float)cnt, 1.0f);
#pragma unroll
        for (int j = 0; j < 4; ++j) av[j] *= inv;
    }

    int fo = lane & 15;
    float y = ba[fo];
#pragma unroll
    for (int k = 0; k < 16; ++k) {
        float ak = __shfl(av[k & 3], k >> 2);
        y += ak * Wa[k * 16 + fo];
        if (MODE != 0) {
            float hk = __shfl(hvv[k & 3], k >> 2);
            y += hk * Wb[k * 16 + fo];
        }
    }
    if (MODE == 0) {
        y = tanhf(y);
    } else {
        float sq = y * y;
        sq += __shfl_xor(sq, 1);
        sq += __shfl_xor(sq, 2);
        sq += __shfl_xor(sq, 4);
        sq += __shfl_xor(sq, 8);
        float nrm = fmaxf(sqrtf(sq), 1e-12f);
        y /= nrm;
        if (MODE == 1) y = tanhf(y);
    }
    if ((lane >> 4) == 0) hout[wid * 16 + fo] = y;
}

// ---------------- Fused MLP: 4 threads per node, all state in VGPRs ----------------
// thread t of a node owns t1[32t..32t+32) and out-chunk acc2[32t..32t+32).
__global__ __launch_bounds__(256, 4)
void k_mlp(const float* __restrict__ h3,
           const float* __restrict__ W1, const float* __restrict__ b1,
           const float* __restrict__ W2, const float* __restrict__ b2,
           const float* __restrict__ W3, const float* __restrict__ b3,
           float* __restrict__ out, int n) {
    int idx = blockIdx.x * blockDim.x + threadIdx.x;
    int node = idx >> 2;
    if (node >= n) return;
    int t = idx & 3;
    int lane = threadIdx.x & 63;
    int lbase = lane & 60;  // quad base

    // h row (16 floats; 4 threads of the node share the same 64B line -> L1 broadcast)
    float h[16];
    {
        const float4* hp = (const float4*)(h3 + node * 16);
#pragma unroll
        for (int q = 0; q < 4; ++q) {
            float4 v = hp[q];
            h[q * 4 + 0] = v.x; h[q * 4 + 1] = v.y; h[q * 4 + 2] = v.z; h[q * 4 + 3] = v.w;
        }
    }

    // layer 1: t1r[jj] = relu(b1[32t+jj] + sum_k h[k] * W1[k*128 + 32t + jj])
    float t1r[32];
    {
        const float4* bp = (const float4*)(b1 + t * 32);
#pragma unroll
        for (int q = 0; q < 8; ++q) {
            float4 v = bp[q];
            t1r[q * 4 + 0] = v.x; t1r[q * 4 + 1] = v.y; t1r[q * 4 + 2] = v.z; t1r[q * 4 + 3] = v.w;
        }
#pragma unroll
        for (int k = 0; k < 16; ++k) {
            const float4* wp = (const float4*)(W1 + k * 128 + t * 32);
            float hk = h[k];
#pragma unroll
            for (int q = 0; q < 8; ++q) {
                float4 v = wp[q];
                t1r[q * 4 + 0] += hk * v.x; t1r[q * 4 + 1] += hk * v.y;
                t1r[q * 4 + 2] += hk * v.z; t1r[q * 4 + 3] += hk * v.w;
            }
        }
#pragma unroll
        for (int j = 0; j < 32; ++j) t1r[j] = fmaxf(t1r[j], 0.f);
    }

    // layer 2: acc[jj] = b2[32t+jj] + sum_k t1[k] * W2[k*128 + 32t + jj]
    float acc[32];
    {
        const float4* bp = (const float4*)(b2 + t * 32);
#pragma unroll
        for (int q = 0; q < 8; ++q) {
            float4 v = bp[q];
            acc[q * 4 + 0] = v.x; acc[q * 4 + 1] = v.y; acc[q * 4 + 2] = v.z; acc[q * 4 + 3] = v.w;
        }
    }
    for (int kt = 0; kt < 4; ++kt) {  // runtime-uniform: shfl source quad-lane
        const float* w2b = W2 + (size_t)(kt * 32) * 128 + t * 32;
#pragma unroll
        for (int kr = 0; kr < 32; ++kr) {
            float tk = __shfl(t1r[kr], lbase | kt);  // static reg index
            const float4* wp = (const float4*)(w2b + kr * 128);
#pragma unroll
            for (int q = 0; q < 8; ++q) {
                float4 v = wp[q];
                acc[q * 4 + 0] += tk * v.x; acc[q * 4 + 1] += tk * v.y;
                acc[q * 4 + 2] += tk * v.z; acc[q * 4 + 3] += tk * v.w;
            }
        }
    }

    // layer 3: partial = sum_jj relu(acc[jj]) * W3[32t+jj]; reduce over quad
    float part = 0.f;
    {
        const float4* wp = (const float4*)(W3 + t * 32);
#pragma unroll
        for (int q = 0; q < 8; ++q) {
            float4 v = wp[q];
            part += fmaxf(acc[q * 4 + 0], 0.f) * v.x + fmaxf(acc[q * 4 + 1], 0.f) * v.y
                  + fmaxf(acc[q * 4 + 2], 0.f) * v.z + fmaxf(acc[q * 4 + 3], 0.f) * v.w;
        }
    }
    part += __shfl_xor(part, 1);
    part += __shfl_xor(part, 2);
    if (t == 0) out[node] = part + b3[0];
}

// ---------------- launch ----------------
extern "C" void kernel_launch(void* const* d_in, const int* in_sizes, int n_in,
                              void* d_out, int out_size, void* d_ws, size_t ws_size,
                              hipStream_t stream) {
    const float* x = (const float*)d_in[0];
    const int* ei = (const int*)d_in[1];
    const float* W_gcn = (const float*)d_in[2];
    const float* b_gcn = (const float*)d_in[3];
    const float* Wl1 = (const float*)d_in[4];
    const float* bl1 = (const float*)d_in[5];
    const float* Wr1 = (const float*)d_in[6];
    const float* Wl2 = (const float*)d_in[7];
    const float* bl2 = (const float*)d_in[8];
    const float* Wr2 = (const float*)d_in[9];
    const float* W1 = (const float*)d_in[10];
    const float* b1 = (const float*)d_in[11];
    const float* W2 = (const float*)d_in[12];
    const float* b2 = (const float*)d_in[13];
    const float* W3 = (const float*)d_in[14];
    const float* b3 = (const float*)d_in[15];

    const int N = in_sizes[0] / 16;
    const int E = in_sizes[1] / 2;
    const int NC = (N + 255) >> 8;
    const int chunk = (E + NBLK - 1) / NBLK;
    const int* src = ei;
    const int* dst = ei + E;

    char* w = (char*)d_ws;
    auto alloc = [&](size_t bytes) {
        void* p = (void*)w;
        w += (bytes + 255) & ~(size_t)255;
        return p;
    };
    int* hist = (int*)alloc((size_t)NBLK * NC * 4);
    int* off = (int*)alloc((size_t)NBLK * NC * 4);
    int* cbase = (int*)alloc((size_t)(NC + 1) * 4);
    int* rowstart = (int*)alloc((size_t)(N + 1) * 4);
    float* dinv = (float*)alloc((size_t)N * 4);
    int* bucketed = (int*)alloc((size_t)E * 4);
    int* csr = (int*)alloc((size_t)E * 4);
    float* h1 = (float*)alloc((size_t)N * 16 * 4);
    float* h2 = (float*)alloc((size_t)N * 16 * 4);
    float* h3 = (float*)alloc((size_t)N * 16 * 4);

    k_hist<<<NBLK, 256, 0, stream>>>(dst, hist, E, NC, chunk);
    k_scan<<<1, 512, 0, stream>>>(hist, off, cbase, rowstart, E, NC, N);
    k_fill<<<NBLK, 256, 0, stream>>>(src, dst, off, cbase, bucketed, E, NC, chunk);
    k_fine<<<NC, 256, 0, stream>>>(bucketed, cbase, csr, rowstart, dinv, N);

    long long conv_threads = (long long)N * 64;
    int blk = 256;
    int ggrid = (int)((conv_threads + blk - 1) / blk);
    k_conv<0><<<ggrid, blk, 0, stream>>>(x,  csr, rowstart, dinv, W_gcn, b_gcn, W_gcn, h1, N);
    k_conv<1><<<ggrid, blk, 0, stream>>>(h1, csr, rowstart, dinv, Wl1, bl1, Wr1, h2, N);
    k_conv<2><<<ggrid, blk, 0, stream>>>(h2, csr, rowstart, dinv, Wl2, bl2, Wr2, h3, N);

    long long mlp_threads = (long long)N * 4;
    int mgrid = (int)((mlp_threads + blk - 1) / blk);
    k_mlp<<<mgrid, blk, 0, stream>>>(h3, W1, b1, W2, b2, W3, b3, (float*)d_out, N);
}

// Round 6
// 836.740 us; speedup vs baseline: 1.5107x; 1.5107x over previous
//
#include <hip/hip_runtime.h>
#include <hip/hip_bf16.h>
#include <math.h>

#define NBLK 512
#define MAXNC 512  // supports N up to 131072 (256 nodes per coarse bucket)

// ---------------- pass A: coarse histogram per block chunk ----------------
__global__ void k_hist(const int* __restrict__ dst, int* __restrict__ hist,
                       int nE, int nc, int chunk) {
    __shared__ int ch[MAXNC];
    int b = blockIdx.x, t = threadIdx.x;
    for (int i = t; i < nc; i += 256) ch[i] = 0;
    __syncthreads();
    int c0 = b * chunk, c1 = min(nE, c0 + chunk);
    for (int e = c0 + t; e < c1; e += 256) atomicAdd(&ch[dst[e] >> 8], 1);
    __syncthreads();
    for (int i = t; i < nc; i += 256) hist[b * nc + i] = ch[i];
}

// ---------------- pass B: per-(block,cb) offsets + cbase scan ----------------
__global__ void k_scan(const int* __restrict__ hist, int* __restrict__ off,
                       int* __restrict__ cbase, int* __restrict__ rowstart,
                       int nE, int nc, int n) {
    __shared__ int sc[512];
    int t = threadIdx.x;  // 512
    int run = 0;
    if (t < nc) {
#pragma unroll 8
        for (int b = 0; b < NBLK; ++b) {
            off[b * nc + t] = run;
            run += hist[b * nc + t];
        }
    }
    sc[t] = (t < nc) ? run : 0;
    __syncthreads();
    for (int d = 1; d < 512; d <<= 1) {
        int v = (t >= d) ? sc[t - d] : 0;
        __syncthreads();
        sc[t] += v;
        __syncthreads();
    }
    if (t < nc) cbase[t] = sc[t] - run;
    if (t == 0) { cbase[nc] = nE; rowstart[n] = nE; }
}

// ---------------- pass C: deterministic scatter into coarse buckets ----------------
__global__ void k_fill(const int* __restrict__ src, const int* __restrict__ dst,
                       const int* __restrict__ off, const int* __restrict__ cbase,
                       int* __restrict__ bucketed, int nE, int nc, int chunk) {
    __shared__ int cur[MAXNC];
    int b = blockIdx.x, t = threadIdx.x;
    for (int i = t; i < nc; i += 256) cur[i] = cbase[i] + off[b * nc + i];
    __syncthreads();
    int c0 = b * chunk, c1 = min(nE, c0 + chunk);
    for (int e = c0 + t; e < c1; e += 256) {
        int d = dst[e];
        int entry = src[e] | ((d & 255) << 17);
        int pos = atomicAdd(&cur[d >> 8], 1);
        bucketed[pos] = entry;
    }
}

// ---------------- pass D: within-bucket sort to per-node CSR + rowstart/dinv ----------------
__global__ void k_fine(const int* __restrict__ bucketed, const int* __restrict__ cbase,
                       int* __restrict__ csr, int* __restrict__ rowstart,
                       float* __restrict__ dinv, int n) {
    __shared__ int cnt[256];
    __shared__ int lrs[256];
    __shared__ int cur[256];
    int cb = blockIdx.x, t = threadIdx.x;
    int e0 = cbase[cb], e1 = cbase[cb + 1];
    cnt[t] = 0;
    __syncthreads();
    for (int e = e0 + t; e < e1; e += 256) atomicAdd(&cnt[(bucketed[e] >> 17) & 255], 1);
    __syncthreads();
    int my = cnt[t];
    lrs[t] = my;
    __syncthreads();
    for (int d = 1; d < 256; d <<= 1) {
        int v = (t >= d) ? lrs[t - d] : 0;
        __syncthreads();
        lrs[t] += v;
        __syncthreads();
    }
    int excl = lrs[t] - my;
    int node = cb * 256 + t;
    if (node < n) {
        rowstart[node] = e0 + excl;
        dinv[node] = rsqrtf((float)(my + 1));
    }
    cur[t] = e0 + excl;
    __syncthreads();
    for (int e = e0 + t; e < e1; e += 256) {
        int entry = bucketed[e];
        int pos = atomicAdd(&cur[(entry >> 17) & 255], 1);
        csr[pos] = entry & 0x1FFFF;
    }
}

// ---------------- conv: wave per node, 16 edge-slots x 4 lanes x float4 ----------------
template <int MODE>
__global__ void k_conv(const float* __restrict__ hin, const int* __restrict__ csr,
                       const int* __restrict__ rowstart, const float* __restrict__ dinv,
                       const float* __restrict__ Wa, const float* __restrict__ ba,
                       const float* __restrict__ Wb,
                       float* __restrict__ hout, int n) {
    int wid = (blockIdx.x * blockDim.x + threadIdx.x) >> 6;
    if (wid >= n) return;
    int lane = threadIdx.x & 63;
    int q = lane >> 2;
    int c = lane & 3;
    int r0 = rowstart[wid], r1 = rowstart[wid + 1];
    int cnt = r1 - r0;
    const int* p = csr + r0 + q;
    int my = (cnt > q) ? ((cnt - q + 15) >> 4) : 0;

    float av[4] = {0.f, 0.f, 0.f, 0.f};
    int s0 = (my > 0) ? p[0] : 0;
    int s1 = (my > 1) ? p[16] : 0;
    for (int t = 0; t < my; ++t) {
        int scur = s0;
        s0 = s1;
        s1 = (t + 2 < my) ? p[(t + 2) * 16] : 0;
        float w = (MODE == 0) ? dinv[scur] : 1.0f;
        float4 v = *(const float4*)(hin + scur * 16 + c * 4);
        av[0] += w * v.x; av[1] += w * v.y; av[2] += w * v.z; av[3] += w * v.w;
    }
#pragma unroll
    for (int m = 4; m <= 32; m <<= 1) {
#pragma unroll
        for (int j = 0; j < 4; ++j) av[j] += __shfl_xor(av[j], m);
    }

    float4 hv4 = *(const float4*)(hin + wid * 16 + c * 4);
    float hvv[4] = {hv4.x, hv4.y, hv4.z, hv4.w};

    if (MODE == 0) {
        float di = dinv[wid];
        float di2 = di * di;
#pragma unroll
        for (int j = 0; j < 4; ++j) av[j] = di * av[j] + di2 * hvv[j];
    } else {
        float inv = 1.0f / fmaxf((float)cnt, 1.0f);
#pragma unroll
        for (int j = 0; j < 4; ++j) av[j] *= inv;
    }

    int fo = lane & 15;
    float y = ba[fo];
#pragma unroll
    for (int k = 0; k < 16; ++k) {
        float ak = __shfl(av[k & 3], k >> 2);
        y += ak * Wa[k * 16 + fo];
        if (MODE != 0) {
            float hk = __shfl(hvv[k & 3], k >> 2);
            y += hk * Wb[k * 16 + fo];
        }
    }
    if (MODE == 0) {
        y = tanhf(y);
    } else {
        float sq = y * y;
        sq += __shfl_xor(sq, 1);
        sq += __shfl_xor(sq, 2);
        sq += __shfl_xor(sq, 4);
        sq += __shfl_xor(sq, 8);
        float nrm = fmaxf(sqrtf(sq), 1e-12f);
        y /= nrm;
        if (MODE == 1) y = tanhf(y);
    }
    if ((lane >> 4) == 0) hout[wid * 16 + fo] = y;
}

// ---------------- Fused MLP: 8 threads per node, live state <= ~56 floats ----------------
// thread t owns t1[16t..16t+16) and output chunk acc[16t..16t+16).
// h[16] is live only in layer 1 (dead after) -> peak register pressure fits 64 VGPRs.
__global__ __launch_bounds__(256, 8)
void k_mlp(const float* __restrict__ h3,
           const float* __restrict__ W1, const float* __restrict__ b1,
           const float* __restrict__ W2, const float* __restrict__ b2,
           const float* __restrict__ W3, const float* __restrict__ b3,
           float* __restrict__ out, int n) {
    int idx = blockIdx.x * blockDim.x + threadIdx.x;
    int node = idx >> 3;
    if (node >= n) return;
    int t = idx & 7;
    int lane = threadIdx.x & 63;
    int gbase = lane & 56;  // 8-lane node-group base

    // layer 1: t1r[j] = relu(b1[16t+j] + sum_k h[k]*W1[k*128 + 16t + j])
    float t1r[16];
    {
        float h[16];
        const float4* hp = (const float4*)(h3 + (size_t)node * 16);
#pragma unroll
        for (int q = 0; q < 4; ++q) {
            float4 v = hp[q];
            h[q * 4 + 0] = v.x; h[q * 4 + 1] = v.y; h[q * 4 + 2] = v.z; h[q * 4 + 3] = v.w;
        }
        const float4* bp = (const float4*)(b1 + t * 16);
#pragma unroll
        for (int q = 0; q < 4; ++q) {
            float4 v = bp[q];
            t1r[q * 4 + 0] = v.x; t1r[q * 4 + 1] = v.y; t1r[q * 4 + 2] = v.z; t1r[q * 4 + 3] = v.w;
        }
#pragma unroll
        for (int k = 0; k < 16; ++k) {
            const float4* wp = (const float4*)(W1 + k * 128 + t * 16);
            float hk = h[k];
#pragma unroll
            for (int q = 0; q < 4; ++q) {
                float4 v = wp[q];
                t1r[q * 4 + 0] += hk * v.x; t1r[q * 4 + 1] += hk * v.y;
                t1r[q * 4 + 2] += hk * v.z; t1r[q * 4 + 3] += hk * v.w;
            }
        }
#pragma unroll
        for (int j = 0; j < 16; ++j) t1r[j] = fmaxf(t1r[j], 0.f);
    }

    // layer 2: acc[j] = b2[16t+j] + sum_k t1[k] * W2[k*128 + 16t + j]
    float acc[16];
    {
        const float4* bp = (const float4*)(b2 + t * 16);
#pragma unroll
        for (int q = 0; q < 4; ++q) {
            float4 v = bp[q];
            acc[q * 4 + 0] = v.x; acc[q * 4 + 1] = v.y; acc[q * 4 + 2] = v.z; acc[q * 4 + 3] = v.w;
        }
    }
    for (int kt = 0; kt < 8; ++kt) {           // runtime-uniform k-group
        int sel = gbase | kt;                  // shfl source lane (uniform per iter)
        const float* w2b = W2 + (size_t)kt * 16 * 128 + t * 16;
#pragma unroll
        for (int kr = 0; kr < 16; ++kr) {      // static t1r index
            float tk = __shfl(t1r[kr], sel);
            const float4* wp = (const float4*)(w2b + kr * 128);
#pragma unroll
            for (int q = 0; q < 4; ++q) {
                float4 v = wp[q];
                acc[q * 4 + 0] += tk * v.x; acc[q * 4 + 1] += tk * v.y;
                acc[q * 4 + 2] += tk * v.z; acc[q * 4 + 3] += tk * v.w;
            }
        }
    }

    // layer 3: partial dot with W3 chunk, reduce over the 8-lane group
    float part = 0.f;
    {
        const float4* wp = (const float4*)(W3 + t * 16);
#pragma unroll
        for (int q = 0; q < 4; ++q) {
            float4 v = wp[q];
            part += fmaxf(acc[q * 4 + 0], 0.f) * v.x + fmaxf(acc[q * 4 + 1], 0.f) * v.y
                  + fmaxf(acc[q * 4 + 2], 0.f) * v.z + fmaxf(acc[q * 4 + 3], 0.f) * v.w;
        }
    }
    part += __shfl_xor(part, 1);
    part += __shfl_xor(part, 2);
    part += __shfl_xor(part, 4);
    if (t == 0) out[node] = part + b3[0];
}

// ---------------- launch ----------------
extern "C" void kernel_launch(void* const* d_in, const int* in_sizes, int n_in,
                              void* d_out, int out_size, void* d_ws, size_t ws_size,
                              hipStream_t stream) {
    const float* x = (const float*)d_in[0];
    const int* ei = (const int*)d_in[1];
    const float* W_gcn = (const float*)d_in[2];
    const float* b_gcn = (const float*)d_in[3];
    const float* Wl1 = (const float*)d_in[4];
    const float* bl1 = (const float*)d_in[5];
    const float* Wr1 = (const float*)d_in[6];
    const float* Wl2 = (const float*)d_in[7];
    const float* bl2 = (const float*)d_in[8];
    const float* Wr2 = (const float*)d_in[9];
    const float* W1 = (const float*)d_in[10];
    const float* b1 = (const float*)d_in[11];
    const float* W2 = (const float*)d_in[12];
    const float* b2 = (const float*)d_in[13];
    const float* W3 = (const float*)d_in[14];
    const float* b3 = (const float*)d_in[15];

    const int N = in_sizes[0] / 16;
    const int E = in_sizes[1] / 2;
    const int NC = (N + 255) >> 8;
    const int chunk = (E + NBLK - 1) / NBLK;
    const int* src = ei;
    const int* dst = ei + E;

    char* w = (char*)d_ws;
    auto alloc = [&](size_t bytes) {
        void* p = (void*)w;
        w += (bytes + 255) & ~(size_t)255;
        return p;
    };
    int* hist = (int*)alloc((size_t)NBLK * NC * 4);
    int* off = (int*)alloc((size_t)NBLK * NC * 4);
    int* cbase = (int*)alloc((size_t)(NC + 1) * 4);
    int* rowstart = (int*)alloc((size_t)(N + 1) * 4);
    float* dinv = (float*)alloc((size_t)N * 4);
    int* bucketed = (int*)alloc((size_t)E * 4);
    int* csr = (int*)alloc((size_t)E * 4);
    float* h1 = (float*)alloc((size_t)N * 16 * 4);
    float* h2 = (float*)alloc((size_t)N * 16 * 4);
    float* h3 = (float*)alloc((size_t)N * 16 * 4);

    k_hist<<<NBLK, 256, 0, stream>>>(dst, hist, E, NC, chunk);
    k_scan<<<1, 512, 0, stream>>>(hist, off, cbase, rowstart, E, NC, N);
    k_fill<<<NBLK, 256, 0, stream>>>(src, dst, off, cbase, bucketed, E, NC, chunk);
    k_fine<<<NC, 256, 0, stream>>>(bucketed, cbase, csr, rowstart, dinv, N);

    long long conv_threads = (long long)N * 64;
    int blk = 256;
    int ggrid = (int)((conv_threads + blk - 1) / blk);
    k_conv<0><<<ggrid, blk, 0, stream>>>(x,  csr, rowstart, dinv, W_gcn, b_gcn, W_gcn, h1, N);
    k_conv<1><<<ggrid, blk, 0, stream>>>(h1, csr, rowstart, dinv, Wl1, bl1, Wr1, h2, N);
    k_conv<2><<<ggrid, blk, 0, stream>>>(h2, csr, rowstart, dinv, Wl2, bl2, Wr2, h3, N);

    long long mlp_threads = (long long)N * 8;
    int mgrid = (int)((mlp_threads + blk - 1) / blk);
    k_mlp<<<mgrid, blk, 0, stream>>>(h3, W1, b1, W2, b2, W3, b3, (float*)d_out, N);
}